// Round 7
// baseline (271.930 us; speedup 1.0000x reference)
//
#include <hip/hip_runtime.h>
#include <hip/hip_bf16.h>

// Pipeline: cast->bf16 (x, Wqkv, Wout), fused QKV GEMM (MFMA + global_load_lds
// + dbuf + RMSNorm/RoPE/V-transpose epilogue), flash attention (causal, GQA,
// LDS-staged KV, paired q-tiles), output GEMM (BN=64).

typedef __bf16 bf16;
typedef bf16 bf16x8 __attribute__((ext_vector_type(8)));
typedef bf16 bf16x4 __attribute__((ext_vector_type(4)));
typedef float f32x4 __attribute__((ext_vector_type(4)));

#define L_SEQ 2048
#define NQH 16
#define NKVH 4

// async global->LDS 16B DMA (gfx950). LDS dest is wave-uniform base + lane*16.
typedef __attribute__((address_space(3))) void lds_void;
typedef const __attribute__((address_space(1))) void glb_void;
__device__ __forceinline__ void async_ld16(const void* g, void* l) {
  __builtin_amdgcn_global_load_lds((glb_void*)g, (lds_void*)l, 16, 0, 0);
}

// ---------------- cast fp32 -> bf16, 4 elems/thread ----------------
__global__ __launch_bounds__(256) void cast_bf16(const float* __restrict__ in,
                                                 bf16* __restrict__ out, int n) {
  int i = (blockIdx.x * 256 + threadIdx.x) * 4;
  if (i < n) {
    float4 v = *(const float4*)&in[i];
    bf16x4 o;
    o[0] = (bf16)v.x; o[1] = (bf16)v.y; o[2] = (bf16)v.z; o[3] = (bf16)v.w;
    *(bf16x4*)&out[i] = o;
  }
}

// ---------------- GEMM core macro-parts (shared by both gemm kernels) -------
// BM=128 x BN tile, BK=32, 4 waves, 16x16x32 bf16 MFMA, dbuf LDS,
// global_load_lds staging w/ source-chunk pre-swizzle (chunk ^= (row>>1)&3).

// ---------------- plain GEMM: C[M,N] = A[M,K] * B[N,K]^T (BN=64) ------------
__global__ __launch_bounds__(256)
void gemm_bt64(const bf16* __restrict__ A, const bf16* __restrict__ B,
               float* __restrict__ C, int M, int N, int K) {
  constexpr int ASZ = 128 * 32, BSZ = 64 * 32;
  __shared__ bf16 As[2 * ASZ];
  __shared__ bf16 Bs[2 * BSZ];
  const int tid = threadIdx.x;
  const int lane = tid & 63, w = tid >> 6;
  const int lq = lane & 15, g = lane >> 4;
  const int wr = w >> 1, wc = w & 1;
  const int bx = blockIdx.x, by = blockIdx.y;

  const bf16* gA[2];
  bf16* ldsA[2];
  const bf16* gB0;
  bf16* ldsB0;
#pragma unroll
  for (int c = 0; c < 2; ++c) {
    int slot = c * 256 + tid;
    int row = slot >> 2, ch = slot & 3;
    int sch = ch ^ ((row >> 1) & 3);
    gA[c] = &A[(size_t)(by * 128 + row) * K + sch * 8];
    ldsA[c] = &As[(c * 256 + w * 64) * 8];
  }
  {
    int row = tid >> 2, ch = tid & 3;
    int sch = ch ^ ((row >> 1) & 3);
    gB0 = &B[(size_t)(bx * 64 + row) * K + sch * 8];
    ldsB0 = &Bs[(w * 64) * 8];
  }

  f32x4 acc[4][2] = {};
  const int nk = K >> 5;
  int cur = 0;

#pragma unroll
  for (int c = 0; c < 2; ++c) async_ld16(gA[c], ldsA[c]);
  async_ld16(gB0, ldsB0);
  __syncthreads();
  for (int kt = 0; kt < nk; ++kt) {
    bf16x8 af[4], bfr[2];
#pragma unroll
    for (int i = 0; i < 4; ++i) {
      int ra = wr * 64 + i * 16 + lq;
      af[i] = *(const bf16x8*)&As[cur * ASZ + ra * 32 + (g ^ ((ra >> 1) & 3)) * 8];
    }
#pragma unroll
    for (int j = 0; j < 2; ++j) {
      int rb = wc * 32 + j * 16 + lq;
      bfr[j] = *(const bf16x8*)&Bs[cur * BSZ + rb * 32 + (g ^ ((rb >> 1) & 3)) * 8];
    }
    if (kt + 1 < nk) {
#pragma unroll
      for (int c = 0; c < 2; ++c) async_ld16(gA[c] + (kt + 1) * 32, ldsA[c] + (cur ^ 1) * ASZ);
      async_ld16(gB0 + (kt + 1) * 32, ldsB0 + (cur ^ 1) * BSZ);
    }
#pragma unroll
    for (int i = 0; i < 4; ++i)
#pragma unroll
      for (int j = 0; j < 2; ++j)
        acc[i][j] = __builtin_amdgcn_mfma_f32_16x16x32_bf16(af[i], bfr[j], acc[i][j], 0, 0, 0);
    __syncthreads();
    cur ^= 1;
  }
#pragma unroll
  for (int i = 0; i < 4; ++i)
#pragma unroll
    for (int j = 0; j < 2; ++j) {
      int row = by * 128 + wr * 64 + i * 16 + g * 4;
      int col = bx * 64 + wc * 32 + j * 16 + lq;
#pragma unroll
      for (int r = 0; r < 4; ++r) C[(size_t)(row + r) * N + col] = acc[i][j][r];
    }
}

// ---------------- fused QKV GEMM + RMSNorm + RoPE + V-transpose -------------
// A = xb[4096 x 2048], B = Wqkv[1536 x 2048] (row-major, K contig).
// BN=64 => each block's tile = 128 seq-rows x ONE head (bx = head 0..23).
//   h<16  : RMSNorm + RoPE + *0.125 -> Qb
//   16-19 : RMSNorm + RoPE          -> Kb
//   20-23 : plain                   -> Vt (transposed (b,kv)[64][2048])
// acc spilled to LDS F (overlaid on As/Bs, dynamic smem) for the epilogue.
__global__ __launch_bounds__(256)
void gemm_qkv_fused(const bf16* __restrict__ A, const bf16* __restrict__ B,
                    const float* __restrict__ qw, const float* __restrict__ kw,
                    bf16* __restrict__ Qb, bf16* __restrict__ Kb,
                    bf16* __restrict__ Vt) {
  constexpr int K = 2048;
  constexpr int ASZ = 128 * 32, BSZ = 64 * 32;
  extern __shared__ char smem[];
  bf16* As = (bf16*)smem;                       // [2*ASZ]
  bf16* Bs = (bf16*)(smem + 2 * ASZ * 2);       // [2*BSZ]
  float* F = (float*)smem;                      // [128][66] overlay (epilogue)
  const int tid = threadIdx.x;
  const int lane = tid & 63, w = tid >> 6;
  const int lq = lane & 15, g = lane >> 4;
  const int wr = w >> 1, wc = w & 1;
  const int bx = blockIdx.x, by = blockIdx.y;

  const bf16* gA[2];
  bf16* ldsA[2];
  const bf16* gB0;
  bf16* ldsB0;
#pragma unroll
  for (int c = 0; c < 2; ++c) {
    int slot = c * 256 + tid;
    int row = slot >> 2, ch = slot & 3;
    int sch = ch ^ ((row >> 1) & 3);
    gA[c] = &A[(size_t)(by * 128 + row) * K + sch * 8];
    ldsA[c] = &As[(c * 256 + w * 64) * 8];
  }
  {
    int row = tid >> 2, ch = tid & 3;
    int sch = ch ^ ((row >> 1) & 3);
    gB0 = &B[(size_t)(bx * 64 + row) * K + sch * 8];
    ldsB0 = &Bs[(w * 64) * 8];
  }

  f32x4 acc[4][2] = {};
  constexpr int nk = K >> 5;
  int cur = 0;

#pragma unroll
  for (int c = 0; c < 2; ++c) async_ld16(gA[c], ldsA[c]);
  async_ld16(gB0, ldsB0);
  __syncthreads();
  for (int kt = 0; kt < nk; ++kt) {
    bf16x8 af[4], bfr[2];
#pragma unroll
    for (int i = 0; i < 4; ++i) {
      int ra = wr * 64 + i * 16 + lq;
      af[i] = *(const bf16x8*)&As[cur * ASZ + ra * 32 + (g ^ ((ra >> 1) & 3)) * 8];
    }
#pragma unroll
    for (int j = 0; j < 2; ++j) {
      int rb = wc * 32 + j * 16 + lq;
      bfr[j] = *(const bf16x8*)&Bs[cur * BSZ + rb * 32 + (g ^ ((rb >> 1) & 3)) * 8];
    }
    if (kt + 1 < nk) {
#pragma unroll
      for (int c = 0; c < 2; ++c) async_ld16(gA[c] + (kt + 1) * 32, ldsA[c] + (cur ^ 1) * ASZ);
      async_ld16(gB0 + (kt + 1) * 32, ldsB0 + (cur ^ 1) * BSZ);
    }
#pragma unroll
    for (int i = 0; i < 4; ++i)
#pragma unroll
      for (int j = 0; j < 2; ++j)
        acc[i][j] = __builtin_amdgcn_mfma_f32_16x16x32_bf16(af[i], bfr[j], acc[i][j], 0, 0, 0);
    __syncthreads();
    cur ^= 1;
  }

  // ---- epilogue: spill acc to F (As/Bs dead after last barrier) ----
#pragma unroll
  for (int i = 0; i < 4; ++i)
#pragma unroll
    for (int j = 0; j < 2; ++j) {
      int row = wr * 64 + i * 16 + g * 4;
      int col = wc * 32 + j * 16 + lq;
#pragma unroll
      for (int r = 0; r < 4; ++r) F[(row + r) * 66 + col] = acc[i][j][r];
    }
  __syncthreads();

  const int h = bx;
  const int b = by >> 4;
  const int l0 = (by & 15) * 128;

  if (h < 20) {
    // ---- RMSNorm + RoPE: 2 threads per row ----
    const int row = tid >> 1;
    const int half = tid & 1;
    const float* Fr = &F[row * 66];
    float ss = 0.f;
#pragma unroll
    for (int c = 0; c < 32; ++c) {
      float v = Fr[half * 32 + c];
      ss += v * v;
    }
    ss += __shfl_xor(ss, 1);
    const float rs = rsqrtf(ss * (1.f / 64.f) + 1e-6f);
    const int l = l0 + row;
    const float* wn = (h < 16) ? qw : kw;
    const float scale = (h < 16) ? 0.125f : 1.f;
    bf16 lo[16], hi[16];
#pragma unroll
    for (int k = 0; k < 16; ++k) {
      int c = half * 16 + k;
      float x1 = Fr[c] * rs * wn[c];
      float x2 = Fr[c + 32] * rs * wn[c + 32];
      float theta = (float)l * exp2f(-(float)c * 0.41524101186280154f);
      float sn, cs;
      sincosf(theta, &sn, &cs);
      lo[k] = (bf16)((x1 * cs - x2 * sn) * scale);
      hi[k] = (bf16)((x1 * sn + x2 * cs) * scale);
    }
    bf16* dst = (h < 16) ? &Qb[((size_t)(b * NQH + h) * L_SEQ + l) * 64]
                         : &Kb[((size_t)(b * NKVH + (h - 16)) * L_SEQ + l) * 64];
    *(bf16x8*)&dst[half * 16] = *(bf16x8*)&lo[0];
    *(bf16x8*)&dst[half * 16 + 8] = *(bf16x8*)&lo[8];
    *(bf16x8*)&dst[half * 16 + 32] = *(bf16x8*)&hi[0];
    *(bf16x8*)&dst[half * 16 + 40] = *(bf16x8*)&hi[8];
  } else {
    // ---- V: transpose to Vt[(b,kv)][d][l] ----
    const int d = tid >> 2;
    const int lg = (tid & 3) * 32;
    bf16 tv[32];
#pragma unroll
    for (int jj = 0; jj < 32; ++jj) tv[jj] = (bf16)F[(lg + jj) * 66 + d];
    bf16* dst = &Vt[(size_t)(b * NKVH + (h - 20)) * 64 * L_SEQ + (size_t)d * L_SEQ + l0 + lg];
#pragma unroll
    for (int c = 0; c < 4; ++c) *(bf16x8*)&dst[c * 8] = *(bf16x8*)&tv[c * 8];
  }
}

// ---------------- flash attention, causal, GQA, LDS-staged KV ----------------
// block = 4 waves, 16 q-rows/wave; 64-key LDS tiles (T14 async-split staging,
// XOR-swizzled rows). Each block processes the q-tile PAIR (p, 31-p) serially
// => uniform 33 key-tiles/block, grid 16x32, no triangular tail.
__global__ __launch_bounds__(256)
void attn(const bf16* __restrict__ Qb, const bf16* __restrict__ Kb,
          const bf16* __restrict__ Vt, bf16* __restrict__ Ao) {
  const int pair = blockIdx.x;  // 0..15
  const int bh = blockIdx.y;    // 0..31
  const int b = bh >> 4, h = bh & 15, kv = h >> 2;
  const int tid = threadIdx.x;
  const int w = tid >> 6, lane = tid & 63;
  const int lq = lane & 15, g = lane >> 4;

  __shared__ bf16 Ks[64][64];       // [key][dim], swizzled chunks
  __shared__ bf16 Vs[64][64];       // [dim][key], swizzled chunks
  __shared__ bf16 Plds[4][16][72];  // per-wave P bounce

  const bf16* Qp = Qb + (size_t)(b * NQH + h) * L_SEQ * 64;
  const bf16* Kp = Kb + (size_t)(b * NKVH + kv) * L_SEQ * 64;
  const bf16* Vp = Vt + (size_t)(b * NKVH + kv) * 64 * L_SEQ;

  const int sr0 = tid >> 3, sc = tid & 7;
  const int sr1 = sr0 + 32;
  const int swc0 = (sc ^ (sr0 & 7)) * 8;  // sr1&7 == sr0&7
  bf16x8 rk0, rk1, rv0, rv1;

  auto load_tile = [&](int k0) {
    rk0 = *(const bf16x8*)&Kp[(size_t)(k0 + sr0) * 64 + sc * 8];
    rk1 = *(const bf16x8*)&Kp[(size_t)(k0 + sr1) * 64 + sc * 8];
    rv0 = *(const bf16x8*)&Vp[(size_t)sr0 * L_SEQ + k0 + sc * 8];
    rv1 = *(const bf16x8*)&Vp[(size_t)sr1 * L_SEQ + k0 + sc * 8];
  };
  auto write_tile = [&]() {
    *(bf16x8*)&Ks[sr0][swc0] = rk0;
    *(bf16x8*)&Ks[sr1][swc0] = rk1;
    *(bf16x8*)&Vs[sr0][swc0] = rv0;
    *(bf16x8*)&Vs[sr1][swc0] = rv1;
  };

  const float L2E = 1.4426950408889634f;

  for (int half = 0; half < 2; ++half) {
    const int qblk = half ? (31 - pair) : pair;
    const int qr0 = qblk * 64 + w * 16;
    const int qg = qr0 + lq;

    bf16x8 qf[2];
    qf[0] = *(const bf16x8*)&Qp[(qr0 + lq) * 64 + g * 8];
    qf[1] = *(const bf16x8*)&Qp[(qr0 + lq) * 64 + 32 + g * 8];

    f32x4 o[4] = {};
    float m = -1e30f, lsum = 0.f;

    const int nkt = qblk + 1;
    load_tile(0);
    __syncthreads();  // prior half's LDS readers done before overwrite
    write_tile();
    __syncthreads();

    for (int kt = 0; kt < nkt; ++kt) {
      const int k0 = kt * 64;
      const bool diag = (kt == nkt - 1);
      if (kt + 1 < nkt) load_tile(k0 + 64);

      f32x4 s[4] = {};
#pragma unroll
      for (int ks = 0; ks < 4; ++ks) {
        if (!diag || ks <= w) {
          const int row = ks * 16 + lq, sw = lq & 7;
          bf16x8 kf0 = *(const bf16x8*)&Ks[row][(g ^ sw) * 8];
          bf16x8 kf1 = *(const bf16x8*)&Ks[row][((g + 4) ^ sw) * 8];
          s[ks] = __builtin_amdgcn_mfma_f32_16x16x32_bf16(kf0, qf[0], s[ks], 0, 0, 0);
          s[ks] = __builtin_amdgcn_mfma_f32_16x16x32_bf16(kf1, qf[1], s[ks], 0, 0, 0);
        }
      }
      if (diag) {
#pragma unroll
        for (int ks = 0; ks < 4; ++ks)
#pragma unroll
          for (int r = 0; r < 4; ++r)
            if (k0 + ks * 16 + g * 4 + r > qg) s[ks][r] = -1e30f;
      }
      float tmax = -1e30f;
#pragma unroll
      for (int ks = 0; ks < 4; ++ks)
#pragma unroll
        for (int r = 0; r < 4; ++r) tmax = fmaxf(tmax, s[ks][r]);
      tmax = fmaxf(tmax, __shfl_xor(tmax, 16));
      tmax = fmaxf(tmax, __shfl_xor(tmax, 32));
      float mnew = fmaxf(m, tmax);
      float alpha = exp2f((m - mnew) * L2E);
      m = mnew;
      float rsum = 0.f;
#pragma unroll
      for (int ks = 0; ks < 4; ++ks) {
        bf16x4 p;
#pragma unroll
        for (int r = 0; r < 4; ++r) {
          float pv = exp2f((s[ks][r] - mnew) * L2E);
          rsum += pv;
          p[r] = (bf16)pv;
        }
        *(bf16x4*)&Plds[w][lq][ks * 16 + g * 4] = p;
      }
      rsum += __shfl_xor(rsum, 16);
      rsum += __shfl_xor(rsum, 32);
      lsum = lsum * alpha + rsum;

      float ar[4];
#pragma unroll
      for (int r = 0; r < 4; ++r) ar[r] = __shfl(alpha, (lane & 48) | (g * 4 + r));
#pragma unroll
      for (int dt = 0; dt < 4; ++dt)
#pragma unroll
        for (int r = 0; r < 4; ++r) o[dt][r] *= ar[r];

      bf16x8 pf0 = *(const bf16x8*)&Plds[w][lq][g * 8];
      bf16x8 pf1 = *(const bf16x8*)&Plds[w][lq][32 + g * 8];
#pragma unroll
      for (int dt = 0; dt < 4; ++dt) {
        const int row = dt * 16 + lq, sw = lq & 7;
        bf16x8 vf0 = *(const bf16x8*)&Vs[row][(g ^ sw) * 8];
        o[dt] = __builtin_amdgcn_mfma_f32_16x16x32_bf16(pf0, vf0, o[dt], 0, 0, 0);
        if (!diag || w >= 2) {
          bf16x8 vf1 = *(const bf16x8*)&Vs[row][((g + 4) ^ sw) * 8];
          o[dt] = __builtin_amdgcn_mfma_f32_16x16x32_bf16(pf1, vf1, o[dt], 0, 0, 0);
        }
      }

      if (kt + 1 < nkt) {
        __syncthreads();
        write_tile();
        __syncthreads();
      }
    }

    float linv = 1.f / lsum;
#pragma unroll
    for (int r = 0; r < 4; ++r) {
      float li = __shfl(linv, (lane & 48) | (g * 4 + r));
      int row = b * L_SEQ + qr0 + g * 4 + r;
#pragma unroll
      for (int dt = 0; dt < 4; ++dt)
        Ao[(size_t)row * 1024 + h * 64 + dt * 16 + lq] = (bf16)(o[dt][r] * li);
    }
  }
}

extern "C" void kernel_launch(void* const* d_in, const int* in_sizes, int n_in,
                              void* d_out, int out_size, void* d_ws, size_t ws_size,
                              hipStream_t stream) {
  const float* x = (const float*)d_in[0];
  const float* Wqkv = (const float*)d_in[1];
  const float* Wout = (const float*)d_in[2];
  const float* qw = (const float*)d_in[3];
  const float* kw = (const float*)d_in[4];
  float* out = (float*)d_out;

  char* ws = (char*)d_ws;
  size_t off = 0;
  auto alloc = [&](size_t bytes) {
    void* p = ws + off;
    off = (off + bytes + 255) & ~(size_t)255;
    return p;
  };
  bf16* xb = (bf16*)alloc(8388608ull * 2);   // x bf16 (4096 x 2048)
  bf16* wqb = (bf16*)alloc(3145728ull * 2);  // W_qkv bf16 (1536 x 2048)
  bf16* wob = (bf16*)alloc(2097152ull * 2);  // W_out bf16 (2048 x 1024)
  bf16* Qb = (bf16*)alloc(4194304ull * 2);   // (2,16,2048,64)
  bf16* Kb = (bf16*)alloc(1048576ull * 2);   // (2,4,2048,64)
  bf16* Vt = (bf16*)alloc(1048576ull * 2);   // (2*4, 64, 2048)
  bf16* Ao = (bf16*)alloc(4194304ull * 2);   // (4096, 1024)

  cast_bf16<<<8192, 256, 0, stream>>>(x, xb, 8388608);
  cast_bf16<<<3072, 256, 0, stream>>>(Wqkv, wqb, 3145728);
  cast_bf16<<<2048, 256, 0, stream>>>(Wout, wob, 2097152);
  // dyn smem: max(As+Bs = 24576 B, F = 128*66*4 = 33792 B)
  gemm_qkv_fused<<<dim3(24, 32), 256, 33792, stream>>>(xb, wqb, qw, kw, Qb, Kb, Vt);
  attn<<<dim3(16, 32), 256, 0, stream>>>(Qb, Kb, Vt, Ao);
  gemm_bt64<<<dim3(32, 32), 256, 0, stream>>>(Ao, wob, out, 4096, 2048, 1024);
}

// Round 8
// 267.839 us; speedup vs baseline: 1.0153x; 1.0153x over previous
//
#include <hip/hip_runtime.h>
#include <hip/hip_bf16.h>

// Pipeline (5 kernels): fused QKV GEMM (fp32-direct load + cvt + MFMA +
// RMSNorm/RoPE/V-transpose epilogue), flash attention (causal, GQA, dbuf
// LDS-staged KV, paired q-tiles), output GEMM (fp32-direct B).

typedef __bf16 bf16;
typedef bf16 bf16x8 __attribute__((ext_vector_type(8)));
typedef bf16 bf16x4 __attribute__((ext_vector_type(4)));
typedef float f32x4 __attribute__((ext_vector_type(4)));

#define L_SEQ 2048
#define NQH 16
#define NKVH 4

// async global->LDS 16B DMA (gfx950). LDS dest is wave-uniform base + lane*16.
typedef __attribute__((address_space(3))) void lds_void;
typedef const __attribute__((address_space(1))) void glb_void;
__device__ __forceinline__ void async_ld16(const void* g, void* l) {
  __builtin_amdgcn_global_load_lds((glb_void*)g, (lds_void*)l, 16, 0, 0);
}

__device__ __forceinline__ bf16x8 cvt8(const float4& a, const float4& b) {
  bf16x8 v;
  v[0] = (bf16)a.x; v[1] = (bf16)a.y; v[2] = (bf16)a.z; v[3] = (bf16)a.w;
  v[4] = (bf16)b.x; v[5] = (bf16)b.y; v[6] = (bf16)b.z; v[7] = (bf16)b.w;
  return v;
}

// ---------------- fused QKV GEMM + RMSNorm + RoPE + V-transpose -------------
// A32 = x fp32 [4096 x 2048], B32 = Wqkv fp32 [1536 x 2048] (row-major).
// BM=128 BN=64 BK=32, 4 waves, dbuf LDS, reg-staged fp32->bf16 cvt staging
// (write-side chunk swizzle: ch ^= (row>>1)&3), ONE barrier per K-step.
// BN=64 => block tile = 128 seq-rows x ONE head (bx = 0..23):
//   h<16: RMSNorm+RoPE+*0.125 -> Qb ; 16-19: RMSNorm+RoPE -> Kb ;
//   20-23: plain -> Vt (transposed (b,kv)[64][2048]).
__global__ __launch_bounds__(256)
void gemm_qkv_fused(const float* __restrict__ A32, const float* __restrict__ B32,
                    const float* __restrict__ qw, const float* __restrict__ kw,
                    bf16* __restrict__ Qb, bf16* __restrict__ Kb,
                    bf16* __restrict__ Vt) {
  constexpr int K = 2048;
  constexpr int ASZ = 128 * 32, BSZ = 64 * 32;
  extern __shared__ char smem[];
  bf16* As = (bf16*)smem;                  // [2*ASZ]
  bf16* Bs = (bf16*)(smem + 2 * ASZ * 2);  // [2*BSZ]
  float* F = (float*)smem;                 // [128][66] overlay (epilogue)
  const int tid = threadIdx.x;
  const int lane = tid & 63, w = tid >> 6;
  const int lq = lane & 15, g = lane >> 4;
  const int wr = w >> 1, wc = w & 1;
  const int bx = blockIdx.x, by = blockIdx.y;

  // staging: slot row/chunk (A has 2 slots/thread, B has 1)
  const int sch = tid & 3;          // chunk 0..3 (8 elems each)
  const int srowA = tid >> 2;       // A rows: srowA, srowA+64
  const int srowB = tid >> 2;       // B row
  const float* gA0 = &A32[(size_t)(by * 128 + srowA) * K + sch * 8];
  const float* gA1 = &A32[(size_t)(by * 128 + 64 + srowA) * K + sch * 8];
  const float* gB0 = &B32[(size_t)(bx * 64 + srowB) * K + sch * 8];
  const int pchA = (sch ^ ((srowA >> 1) & 3)) * 8;  // same for srowA+64
  const int pchB = (sch ^ ((srowB >> 1) & 3)) * 8;

  float4 ra0[2], ra1[2], rb[2];
  auto load_regs = [&](int kt) {
    const float* p0 = gA0 + kt * 32;
    ra0[0] = *(const float4*)p0; ra0[1] = *(const float4*)(p0 + 4);
    const float* p1 = gA1 + kt * 32;
    ra1[0] = *(const float4*)p1; ra1[1] = *(const float4*)(p1 + 4);
    const float* pb = gB0 + kt * 32;
    rb[0] = *(const float4*)pb; rb[1] = *(const float4*)(pb + 4);
  };
  auto cvt_write = [&](int buf) {
    *(bf16x8*)&As[buf * ASZ + srowA * 32 + pchA] = cvt8(ra0[0], ra0[1]);
    *(bf16x8*)&As[buf * ASZ + (64 + srowA) * 32 + pchA] = cvt8(ra1[0], ra1[1]);
    *(bf16x8*)&Bs[buf * BSZ + srowB * 32 + pchB] = cvt8(rb[0], rb[1]);
  };

  f32x4 acc[4][2] = {};
  constexpr int nk = K >> 5;
  int cur = 0;

  load_regs(0);
  cvt_write(0);
  __syncthreads();
  for (int kt = 0; kt < nk; ++kt) {
    bf16x8 af[4], bfr[2];
#pragma unroll
    for (int i = 0; i < 4; ++i) {
      int ra = wr * 64 + i * 16 + lq;
      af[i] = *(const bf16x8*)&As[cur * ASZ + ra * 32 + (g ^ ((ra >> 1) & 3)) * 8];
    }
#pragma unroll
    for (int j = 0; j < 2; ++j) {
      int rbr = wc * 32 + j * 16 + lq;
      bfr[j] = *(const bf16x8*)&Bs[cur * BSZ + rbr * 32 + (g ^ ((rbr >> 1) & 3)) * 8];
    }
    if (kt + 1 < nk) load_regs(kt + 1);  // issue early; lands under MFMAs
#pragma unroll
    for (int i = 0; i < 4; ++i)
#pragma unroll
      for (int j = 0; j < 2; ++j)
        acc[i][j] = __builtin_amdgcn_mfma_f32_16x16x32_bf16(af[i], bfr[j], acc[i][j], 0, 0, 0);
    if (kt + 1 < nk) cvt_write(cur ^ 1);  // vmcnt wait + cvt + ds_write
    __syncthreads();
    cur ^= 1;
  }

  // ---- epilogue: spill acc to F (As/Bs dead after last barrier) ----
#pragma unroll
  for (int i = 0; i < 4; ++i)
#pragma unroll
    for (int j = 0; j < 2; ++j) {
      int row = wr * 64 + i * 16 + g * 4;
      int col = wc * 32 + j * 16 + lq;
#pragma unroll
      for (int r = 0; r < 4; ++r) F[(row + r) * 66 + col] = acc[i][j][r];
    }
  __syncthreads();

  const int h = bx;
  const int b = by >> 4;
  const int l0 = (by & 15) * 128;

  if (h < 20) {
    // ---- RMSNorm + RoPE: 2 threads per row ----
    const int row = tid >> 1;
    const int half = tid & 1;
    const float* Fr = &F[row * 66];
    float ss = 0.f;
#pragma unroll
    for (int c = 0; c < 32; ++c) {
      float v = Fr[half * 32 + c];
      ss += v * v;
    }
    ss += __shfl_xor(ss, 1);
    const float rs = rsqrtf(ss * (1.f / 64.f) + 1e-6f);
    const int l = l0 + row;
    const float* wn = (h < 16) ? qw : kw;
    const float scale = (h < 16) ? 0.125f : 1.f;
    bf16 lo[16], hi[16];
#pragma unroll
    for (int k = 0; k < 16; ++k) {
      int c = half * 16 + k;
      float x1 = Fr[c] * rs * wn[c];
      float x2 = Fr[c + 32] * rs * wn[c + 32];
      float theta = (float)l * exp2f(-(float)c * 0.41524101186280154f);
      float sn, cs;
      sincosf(theta, &sn, &cs);
      lo[k] = (bf16)((x1 * cs - x2 * sn) * scale);
      hi[k] = (bf16)((x1 * sn + x2 * cs) * scale);
    }
    bf16* dst = (h < 16) ? &Qb[((size_t)(b * NQH + h) * L_SEQ + l) * 64]
                         : &Kb[((size_t)(b * NKVH + (h - 16)) * L_SEQ + l) * 64];
    *(bf16x8*)&dst[half * 16] = *(bf16x8*)&lo[0];
    *(bf16x8*)&dst[half * 16 + 8] = *(bf16x8*)&lo[8];
    *(bf16x8*)&dst[half * 16 + 32] = *(bf16x8*)&hi[0];
    *(bf16x8*)&dst[half * 16 + 40] = *(bf16x8*)&hi[8];
  } else {
    // ---- V: transpose to Vt[(b,kv)][d][l] ----
    const int d = tid >> 2;
    const int lg = (tid & 3) * 32;
    bf16 tv[32];
#pragma unroll
    for (int jj = 0; jj < 32; ++jj) tv[jj] = (bf16)F[(lg + jj) * 66 + d];
    bf16* dst = &Vt[(size_t)(b * NKVH + (h - 20)) * 64 * L_SEQ + (size_t)d * L_SEQ + l0 + lg];
#pragma unroll
    for (int c = 0; c < 4; ++c) *(bf16x8*)&dst[c * 8] = *(bf16x8*)&tv[c * 8];
  }
}

// ---------------- output GEMM: C[M,N] = A[M,K] * B32[N,K]^T (BN=64) ---------
// A bf16 via global_load_lds (pre-swizzled source); B fp32 reg-staged + cvt.
__global__ __launch_bounds__(256)
void gemm_out(const bf16* __restrict__ A, const float* __restrict__ B32,
              float* __restrict__ C, int M, int N, int K) {
  constexpr int ASZ = 128 * 32, BSZ = 64 * 32;
  __shared__ bf16 As[2 * ASZ];
  __shared__ bf16 Bs[2 * BSZ];
  const int tid = threadIdx.x;
  const int lane = tid & 63, w = tid >> 6;
  const int lq = lane & 15, g = lane >> 4;
  const int wr = w >> 1, wc = w & 1;
  const int bx = blockIdx.x, by = blockIdx.y;

  // A: async staging, source chunk pre-swizzled, LDS linear
  const bf16* gA[2];
  bf16* ldsA[2];
#pragma unroll
  for (int c = 0; c < 2; ++c) {
    int slot = c * 256 + tid;
    int row = slot >> 2, ch = slot & 3;
    int sch = ch ^ ((row >> 1) & 3);
    gA[c] = &A[(size_t)(by * 128 + row) * K + sch * 8];
    ldsA[c] = &As[(c * 256 + w * 64) * 8];
  }
  // B: reg-staged fp32
  const int sch = tid & 3;
  const int srowB = tid >> 2;
  const float* gB0 = &B32[(size_t)(bx * 64 + srowB) * K + sch * 8];
  const int pchB = (sch ^ ((srowB >> 1) & 3)) * 8;
  float4 rb[2];

  f32x4 acc[4][2] = {};
  const int nk = K >> 5;
  int cur = 0;

#pragma unroll
  for (int c = 0; c < 2; ++c) async_ld16(gA[c], ldsA[c]);
  rb[0] = *(const float4*)gB0; rb[1] = *(const float4*)(gB0 + 4);
  *(bf16x8*)&Bs[srowB * 32 + pchB] = cvt8(rb[0], rb[1]);
  __syncthreads();
  for (int kt = 0; kt < nk; ++kt) {
    bf16x8 af[4], bfr[2];
#pragma unroll
    for (int i = 0; i < 4; ++i) {
      int ra = wr * 64 + i * 16 + lq;
      af[i] = *(const bf16x8*)&As[cur * ASZ + ra * 32 + (g ^ ((ra >> 1) & 3)) * 8];
    }
#pragma unroll
    for (int j = 0; j < 2; ++j) {
      int rbr = wc * 32 + j * 16 + lq;
      bfr[j] = *(const bf16x8*)&Bs[cur * BSZ + rbr * 32 + (g ^ ((rbr >> 1) & 3)) * 8];
    }
    if (kt + 1 < nk) {
#pragma unroll
      for (int c = 0; c < 2; ++c) async_ld16(gA[c] + (kt + 1) * 32, ldsA[c] + (cur ^ 1) * ASZ);
      const float* pb = gB0 + (kt + 1) * 32;
      rb[0] = *(const float4*)pb; rb[1] = *(const float4*)(pb + 4);
    }
#pragma unroll
    for (int i = 0; i < 4; ++i)
#pragma unroll
      for (int j = 0; j < 2; ++j)
        acc[i][j] = __builtin_amdgcn_mfma_f32_16x16x32_bf16(af[i], bfr[j], acc[i][j], 0, 0, 0);
    if (kt + 1 < nk)
      *(bf16x8*)&Bs[(cur ^ 1) * BSZ + srowB * 32 + pchB] = cvt8(rb[0], rb[1]);
    __syncthreads();
    cur ^= 1;
  }
#pragma unroll
  for (int i = 0; i < 4; ++i)
#pragma unroll
    for (int j = 0; j < 2; ++j) {
      int row = by * 128 + wr * 64 + i * 16 + g * 4;
      int col = bx * 64 + wc * 32 + j * 16 + lq;
#pragma unroll
      for (int r = 0; r < 4; ++r) C[(size_t)(row + r) * N + col] = acc[i][j][r];
    }
}

// ---------------- flash attention, causal, GQA, dbuf LDS-staged KV ----------
// block = 4 waves, 16 q-rows/wave; 64-key tiles double-buffered in LDS:
// ONE __syncthreads per tile (write next tile into buf^1 while reading buf).
// Paired q-tiles (p, 31-p) serially => uniform 33 key-tiles/block.
__global__ __launch_bounds__(256)
void attn(const bf16* __restrict__ Qb, const bf16* __restrict__ Kb,
          const bf16* __restrict__ Vt, bf16* __restrict__ Ao) {
  const int pair = blockIdx.x;  // 0..15
  const int bh = blockIdx.y;    // 0..31
  const int b = bh >> 4, h = bh & 15, kv = h >> 2;
  const int tid = threadIdx.x;
  const int w = tid >> 6, lane = tid & 63;
  const int lq = lane & 15, g = lane >> 4;

  __shared__ bf16 Ks[2][64][64];    // [buf][key][dim], swizzled chunks
  __shared__ bf16 Vs[2][64][64];    // [buf][dim][key], swizzled chunks
  __shared__ bf16 Plds[4][16][72];  // per-wave P bounce

  const bf16* Qp = Qb + (size_t)(b * NQH + h) * L_SEQ * 64;
  const bf16* Kp = Kb + (size_t)(b * NKVH + kv) * L_SEQ * 64;
  const bf16* Vp = Vt + (size_t)(b * NKVH + kv) * 64 * L_SEQ;

  const int sr0 = tid >> 3, sc = tid & 7;
  const int sr1 = sr0 + 32;
  const int swc0 = (sc ^ (sr0 & 7)) * 8;  // sr1&7 == sr0&7
  bf16x8 rk0, rk1, rv0, rv1;

  auto load_tile = [&](int k0) {
    rk0 = *(const bf16x8*)&Kp[(size_t)(k0 + sr0) * 64 + sc * 8];
    rk1 = *(const bf16x8*)&Kp[(size_t)(k0 + sr1) * 64 + sc * 8];
    rv0 = *(const bf16x8*)&Vp[(size_t)sr0 * L_SEQ + k0 + sc * 8];
    rv1 = *(const bf16x8*)&Vp[(size_t)sr1 * L_SEQ + k0 + sc * 8];
  };
  auto write_tile = [&](int buf) {
    *(bf16x8*)&Ks[buf][sr0][swc0] = rk0;
    *(bf16x8*)&Ks[buf][sr1][swc0] = rk1;
    *(bf16x8*)&Vs[buf][sr0][swc0] = rv0;
    *(bf16x8*)&Vs[buf][sr1][swc0] = rv1;
  };

  const float L2E = 1.4426950408889634f;

  for (int half = 0; half < 2; ++half) {
    const int qblk = half ? (31 - pair) : pair;
    const int qr0 = qblk * 64 + w * 16;
    const int qg = qr0 + lq;

    bf16x8 qf[2];
    qf[0] = *(const bf16x8*)&Qp[(qr0 + lq) * 64 + g * 8];
    qf[1] = *(const bf16x8*)&Qp[(qr0 + lq) * 64 + 32 + g * 8];

    f32x4 o[4] = {};
    float m = -1e30f, lsum = 0.f;

    const int nkt = qblk + 1;
    int cur = 0;
    load_tile(0);
    __syncthreads();  // prior half's LDS readers done before overwrite
    write_tile(0);
    __syncthreads();

    for (int kt = 0; kt < nkt; ++kt) {
      const int k0 = kt * 64;
      const bool diag = (kt == nkt - 1);
      if (kt + 1 < nkt) load_tile(k0 + 64);  // async: hides under compute

      // ---- QK^T: s[ks] holds scores for query lq, keys k0+ks*16+g*4+r ----
      f32x4 s[4] = {};
#pragma unroll
      for (int ks = 0; ks < 4; ++ks) {
        if (!diag || ks <= w) {  // skip fully-masked frags on diag tile
          const int row = ks * 16 + lq, sw = lq & 7;
          bf16x8 kf0 = *(const bf16x8*)&Ks[cur][row][(g ^ sw) * 8];
          bf16x8 kf1 = *(const bf16x8*)&Ks[cur][row][((g + 4) ^ sw) * 8];
          s[ks] = __builtin_amdgcn_mfma_f32_16x16x32_bf16(kf0, qf[0], s[ks], 0, 0, 0);
          s[ks] = __builtin_amdgcn_mfma_f32_16x16x32_bf16(kf1, qf[1], s[ks], 0, 0, 0);
        }
      }
      if (diag) {
#pragma unroll
        for (int ks = 0; ks < 4; ++ks)
#pragma unroll
          for (int r = 0; r < 4; ++r)
            if (k0 + ks * 16 + g * 4 + r > qg) s[ks][r] = -1e30f;
      }
      float tmax = -1e30f;
#pragma unroll
      for (int ks = 0; ks < 4; ++ks)
#pragma unroll
        for (int r = 0; r < 4; ++r) tmax = fmaxf(tmax, s[ks][r]);
      tmax = fmaxf(tmax, __shfl_xor(tmax, 16));
      tmax = fmaxf(tmax, __shfl_xor(tmax, 32));
      float mnew = fmaxf(m, tmax);
      float alpha = exp2f((m - mnew) * L2E);
      m = mnew;
      float rsum = 0.f;
#pragma unroll
      for (int ks = 0; ks < 4; ++ks) {
        bf16x4 p;
#pragma unroll
        for (int r = 0; r < 4; ++r) {
          float pv = exp2f((s[ks][r] - mnew) * L2E);
          rsum += pv;
          p[r] = (bf16)pv;
        }
        *(bf16x4*)&Plds[w][lq][ks * 16 + g * 4] = p;
      }
      rsum += __shfl_xor(rsum, 16);
      rsum += __shfl_xor(rsum, 32);
      lsum = lsum * alpha + rsum;

      float ar[4];
#pragma unroll
      for (int r = 0; r < 4; ++r) ar[r] = __shfl(alpha, (lane & 48) | (g * 4 + r));
#pragma unroll
      for (int dt = 0; dt < 4; ++dt)
#pragma unroll
        for (int r = 0; r < 4; ++r) o[dt][r] *= ar[r];

      bf16x8 pf0 = *(const bf16x8*)&Plds[w][lq][g * 8];
      bf16x8 pf1 = *(const bf16x8*)&Plds[w][lq][32 + g * 8];
#pragma unroll
      for (int dt = 0; dt < 4; ++dt) {
        const int row = dt * 16 + lq, sw = lq & 7;
        bf16x8 vf0 = *(const bf16x8*)&Vs[cur][row][(g ^ sw) * 8];
        o[dt] = __builtin_amdgcn_mfma_f32_16x16x32_bf16(pf0, vf0, o[dt], 0, 0, 0);
        if (!diag || w >= 2) {
          bf16x8 vf1 = *(const bf16x8*)&Vs[cur][row][((g + 4) ^ sw) * 8];
          o[dt] = __builtin_amdgcn_mfma_f32_16x16x32_bf16(pf1, vf1, o[dt], 0, 0, 0);
        }
      }

      if (kt + 1 < nkt) write_tile(cur ^ 1);  // vmcnt wait + ds_write
      __syncthreads();                        // single barrier per tile
      cur ^= 1;
    }

    float linv = 1.f / lsum;
#pragma unroll
    for (int r = 0; r < 4; ++r) {
      float li = __shfl(linv, (lane & 48) | (g * 4 + r));
      int row = b * L_SEQ + qr0 + g * 4 + r;
#pragma unroll
      for (int dt = 0; dt < 4; ++dt)
        Ao[(size_t)row * 1024 + h * 64 + dt * 16 + lq] = (bf16)(o[dt][r] * li);
    }
  }
}

extern "C" void kernel_launch(void* const* d_in, const int* in_sizes, int n_in,
                              void* d_out, int out_size, void* d_ws, size_t ws_size,
                              hipStream_t stream) {
  const float* x = (const float*)d_in[0];
  const float* Wqkv = (const float*)d_in[1];
  const float* Wout = (const float*)d_in[2];
  const float* qw = (const float*)d_in[3];
  const float* kw = (const float*)d_in[4];
  float* out = (float*)d_out;

  char* ws = (char*)d_ws;
  size_t off = 0;
  auto alloc = [&](size_t bytes) {
    void* p = ws + off;
    off = (off + bytes + 255) & ~(size_t)255;
    return p;
  };
  bf16* Qb = (bf16*)alloc(4194304ull * 2);  // (2,16,2048,64)
  bf16* Kb = (bf16*)alloc(1048576ull * 2);  // (2,4,2048,64)
  bf16* Vt = (bf16*)alloc(1048576ull * 2);  // (2*4, 64, 2048)
  bf16* Ao = (bf16*)alloc(4194304ull * 2);  // (4096, 1024)

  // dyn smem: max(As+Bs = 24576 B, F = 128*66*4 = 33792 B)
  gemm_qkv_fused<<<dim3(24, 32), 256, 33792, stream>>>(x, Wqkv, qw, kw, Qb, Kb, Vt);
  attn<<<dim3(16, 32), 256, 0, stream>>>(Qb, Kb, Vt, Ao);
  gemm_out<<<dim3(32, 32), 256, 0, stream>>>(Ao, Wout, out, 4096, 2048, 1024);
}